// Round 4
// baseline (145.221 us; speedup 1.0000x reference)
//
#include <hip/hip_runtime.h>
#include <math.h>

#define Wd 256
#define Hd 256
#define KW 11
#define PAD 5
#define OUT_R 32              // output rows per block (band)
#define NCHUNK 4              // 4*11 = 44 h-rows staged >= OUT_R + 10
#define LPAD 6                // left pad in float2 units; data starts 16B-aligned
#define SROW (LPAD + Wd + 6)  // 268 float2 per row
#define BLOCK 256

__device__ __forceinline__ float rfl(float v) {
    return __int_as_float(__builtin_amdgcn_readfirstlane(__float_as_int(v)));
}

// One block = one 32-row band of one (n,c) plane. 256 threads = 1 thread/column.
// img1/img2 interleaved as float2 in LDS -> horizontal 11-tap pass is 11
// ds_read_b64 per element (stride-8B, full-BW). Vertical 11-tap pass runs in a
// 4-channel register ring with static indices (h-row i = ch*11+j => slot j).
// Channels: A=conv(x), B=conv(y), Q=conv(x^2+y^2), P=conv(x*y).
__global__ __launch_bounds__(BLOCK, 3) void ssim_band_kernel(
    const float* __restrict__ img1, const float* __restrict__ img2,
    const float* __restrict__ window, float* __restrict__ partials)
{
    __shared__ __align__(16) float2 s[KW][SROW];   // 11*268*8 = 23.0 KB
    __shared__ float red[BLOCK / 64];

    const float C1 = 1e-4f, C2 = 9e-4f;
    const int t = threadIdx.x;
    const int band = blockIdx.x;     // 0..7
    const int plane = blockIdx.y;    // 0..143
    const float* __restrict__ p1 = img1 + (size_t)plane * (Hd * Wd);
    const float* __restrict__ p2 = img2 + (size_t)plane * (Hd * Wd);

    // Separable 1D weights from 2D window (win2d = a outer a, sum a = 1);
    // wave-uniform -> pin to SGPRs via readfirstlane.
    float wl[KW];
    {
        float c = sqrtf(window[5 * KW + 5]);
        #pragma unroll
        for (int k = 0; k < KW; ++k)
            wl[k] = rfl(window[k * KW + 5] / c);
    }

    // Zero halo float2 cells once (staging never writes them).
    // Taps read float2 idx t+1+k (k=0..10): cols -5..-1 -> idx 1..5,
    // cols 256..260 -> idx 262..266.
    if (t < 110) {
        int r = t / 10, c = t % 10;
        int idx = (c < PAD) ? (1 + c) : (257 + c);
        s[r][idx] = make_float2(0.f, 0.f);
    }

    float rA[KW], rB[KW], rQ[KW], rP[KW];
    float acc = 0.f;
    const int ghbase = band * OUT_R - PAD;  // image row of local h index 0

    #pragma unroll 1
    for (int ch = 0; ch < NCHUNK; ++ch) {
        __syncthreads();  // previous chunk's readers done before overwrite
        // --- stage 11 rows, both images interleaved: lane = 2 columns ---
        // item i: r = i>>7 (row), h = i&127 (2-col group: cols 2h, 2h+1)
        {
            const int gb = ghbase + ch * KW;
            #pragma unroll
            for (int it = 0; it < 6; ++it) {
                int i = t + it * BLOCK;
                if (i < KW * 128) {
                    int r = i >> 7, h = i & 127;
                    int g = gb + r;
                    bool ok = (g >= 0) & (g < Hd);
                    int gc = min(max(g, 0), Hd - 1);
                    float2 x = *(const float2*)(p1 + (size_t)gc * Wd + 2 * h);
                    float2 y = *(const float2*)(p2 + (size_t)gc * Wd + 2 * h);
                    float4 v = ok ? make_float4(x.x, y.x, x.y, y.y)
                                  : make_float4(0.f, 0.f, 0.f, 0.f);
                    *(float4*)&s[r][LPAD + 2 * h] = v;   // 16B-aligned, contiguous
                }
            }
        }
        __syncthreads();

        // --- 11 h-rows: horizontal pass into ring slot j, emit when full ---
        #pragma unroll
        for (int j = 0; j < KW; ++j) {
            float a = 0.f, b = 0.f, qq = 0.f, pp = 0.f;
            #pragma unroll
            for (int k = 0; k < KW; ++k) {
                float w = wl[k];
                float2 v = s[j][t + 1 + k];   // ds_read_b64
                float x = v.x, y = v.y;
                a = fmaf(w, x, a);
                b = fmaf(w, y, b);
                float xy = x * y;
                float ss = fmaf(y, y, x * x);
                pp = fmaf(w, xy, pp);
                qq = fmaf(w, ss, qq);
            }
            rA[j] = a; rB[j] = b; rQ[j] = qq; rP[j] = pp;

            const int i = ch * KW + j;             // local h index (uniform)
            if (i >= 10 && i < OUT_R + 10) {       // output row o = band*OUT_R + i - 10
                float mu1 = 0.f, mu2 = 0.f, sq = 0.f, sp = 0.f;
                #pragma unroll
                for (int m = 0; m < KW; ++m) {     // ring slot for h-row (o-5+m)
                    const int sidx = (j + 1 + m) % KW;  // static per (j,m)
                    float w = wl[m];
                    mu1 = fmaf(w, rA[sidx], mu1);
                    mu2 = fmaf(w, rB[sidx], mu2);
                    sq  = fmaf(w, rQ[sidx], sq);
                    sp  = fmaf(w, rP[sidx], sp);
                }
                float mu1sq = mu1 * mu1, mu2sq = mu2 * mu2, mu12 = mu1 * mu2;
                float musum = mu1sq + mu2sq;
                float num = (2.f * mu12 + C1) * (2.f * (sp - mu12) + C2);
                float den = (musum + C1) * ((sq - musum) + C2);
                acc += num * __builtin_amdgcn_rcpf(den);
            }
        }
    }

    // --- block reduction ---
    #pragma unroll
    for (int off = 32; off > 0; off >>= 1)
        acc += __shfl_down(acc, off, 64);
    int wave = t >> 6;
    if ((t & 63) == 0) red[wave] = acc;
    __syncthreads();
    if (t == 0)
        partials[plane * gridDim.x + band] = red[0] + red[1] + red[2] + red[3];
}

__global__ __launch_bounds__(BLOCK) void ssim_reduce_kernel(
    const float* __restrict__ partials, float* __restrict__ out,
    int n, double inv_count)
{
    __shared__ double red[BLOCK / 64];
    double s = 0.0;
    for (int i = threadIdx.x; i < n; i += BLOCK) s += (double)partials[i];
    #pragma unroll
    for (int off = 32; off > 0; off >>= 1)
        s += __shfl_down(s, off, 64);
    int wave = threadIdx.x >> 6;
    if ((threadIdx.x & 63) == 0) red[wave] = s;
    __syncthreads();
    if (threadIdx.x == 0) {
        double total = red[0] + red[1] + red[2] + red[3];
        out[0] = (float)(1.0 - total * inv_count);
    }
}

extern "C" void kernel_launch(void* const* d_in, const int* in_sizes, int n_in,
                              void* d_out, int out_size, void* d_ws, size_t ws_size,
                              hipStream_t stream) {
    const float* img1   = (const float*)d_in[0];
    const float* img2   = (const float*)d_in[1];
    const float* window = (const float*)d_in[2];
    float* out = (float*)d_out;
    float* partials = (float*)d_ws;

    const int planes = 16 * 9;            // 144
    const int bands = Hd / OUT_R;         // 8
    const int nblocks = planes * bands;   // 1152

    dim3 grid(bands, planes);
    ssim_band_kernel<<<grid, BLOCK, 0, stream>>>(img1, img2, window, partials);

    const double inv_count = 1.0 / ((double)planes * Hd * Wd);
    ssim_reduce_kernel<<<1, BLOCK, 0, stream>>>(partials, out, nblocks, inv_count);
}

// Round 5
// 137.921 us; speedup vs baseline: 1.0529x; 1.0529x over previous
//
#include <hip/hip_runtime.h>
#include <math.h>

#define Wd 256
#define Hd 256
#define KW 11
#define PAD 5
#define OUT_R 32              // output rows per block (band)
#define NCHUNK 4              // 4*11 = 44 h-rows staged >= OUT_R + 10
#define LPAD 6                // left pad in float2 units; data starts 16B-aligned
#define SROW (LPAD + Wd + 6)  // 268 float2 per row (2144 B stride, 16B-aligned)
#define BLOCK 256

typedef float v2f __attribute__((ext_vector_type(2)));

__device__ __forceinline__ float rfl(float v) {
    return __int_as_float(__builtin_amdgcn_readfirstlane(__float_as_int(v)));
}

// One block = one 32-row band of one (n,c) plane; 256 threads = 1 thread/col.
// img1/img2 interleaved as (x,y) pairs in LDS -> horizontal tap = ds_read_b64
// feeding one v_pk_fma_f32 for the (A,B) channels. Vertical 11-tap pass runs
// in a channel-packed register ring: rAB=(a,b), rQP=(q,p), 22 v2f = 44 VGPRs,
// static slot indices (h-row i = ch*11+j => slot j). Double-buffered LDS
// (47 KB) pipelines staging AND forces the compiler's occupancy target to
// 3 waves/EU so the ring stays in architectural VGPRs (no accvgpr copies).
__global__ __launch_bounds__(BLOCK, 3) void ssim_band_kernel(
    const float* __restrict__ img1, const float* __restrict__ img2,
    const float* __restrict__ window, float* __restrict__ out, float scale)
{
    __shared__ __align__(16) v2f s[2][KW][SROW];   // 2*11*268*8 = 47.2 KB
    __shared__ float red[BLOCK / 64];

    const float C1 = 1e-4f, C2 = 9e-4f;
    const int t = threadIdx.x;
    const int band = blockIdx.x;     // 0..7
    const int plane = blockIdx.y;    // 0..143
    const float* __restrict__ p1 = img1 + (size_t)plane * (Hd * Wd);
    const float* __restrict__ p2 = img2 + (size_t)plane * (Hd * Wd);

    // Separable 1D weights (win2d = a outer a, sum a = 1); pin to SGPRs.
    float wl[KW];
    {
        float c = sqrtf(window[5 * KW + 5]);
        #pragma unroll
        for (int k = 0; k < KW; ++k)
            wl[k] = rfl(window[k * KW + 5] / c);
    }

    // Zero halo cells once in BOTH buffers (stores only write idx 6..261).
    // Taps read idx t+1+k: cols -5..-1 -> idx 1..5, cols 256..260 -> 262..266.
    if (t < 110) {
        int r = t / 10, c = t % 10;
        int idx = (c < PAD) ? (1 + c) : (257 + c);
        v2f z; z.x = 0.f; z.y = 0.f;
        s[0][r][idx] = z;
        s[1][r][idx] = z;
    }

    const int ghbase = band * OUT_R - PAD;  // image row of local h index 0

    // --- staging helpers: 704 items = 11 rows x 64 col-quads ---
    float4 pa[3], pb[3];
    auto load_chunk = [&](int ch) {
        const int gb = ghbase + ch * KW;
        #pragma unroll
        for (int it = 0; it < 3; ++it) {
            int i = t + (it << 8);
            if (i < KW * 64) {
                int r = i >> 6, q = i & 63;
                int g = gb + r;
                int gc = min(max(g, 0), Hd - 1);
                const float* b1 = p1 + (size_t)gc * Wd + (q << 2);
                const float* b2 = p2 + (size_t)gc * Wd + (q << 2);
                pa[it] = *(const float4*)b1;
                pb[it] = *(const float4*)b2;
            }
        }
    };
    auto store_chunk = [&](int buf, int ch) {
        const int gb = ghbase + ch * KW;
        #pragma unroll
        for (int it = 0; it < 3; ++it) {
            int i = t + (it << 8);
            if (i < KW * 64) {
                int r = i >> 6, q = i & 63;
                int g = gb + r;
                bool ok = (g >= 0) & (g < Hd);
                float4 x = pa[it], y = pb[it];
                if (!ok) { x = make_float4(0.f, 0.f, 0.f, 0.f);
                           y = make_float4(0.f, 0.f, 0.f, 0.f); }
                *(float4*)&s[buf][r][LPAD + (q << 2)]     = make_float4(x.x, y.x, x.y, y.y);
                *(float4*)&s[buf][r][LPAD + (q << 2) + 2] = make_float4(x.z, y.z, x.w, y.w);
            }
        }
    };

    v2f rAB[KW], rQP[KW];
    float acc = 0.f;

    load_chunk(0);
    store_chunk(0, 0);
    __syncthreads();

    #pragma unroll 1
    for (int ch = 0; ch < NCHUNK; ++ch) {
        if (ch + 1 < NCHUNK) load_chunk(ch + 1);   // issue loads before compute

        const v2f* base = &s[ch & 1][0][t + 1];    // all taps: immediate offsets

        #pragma unroll
        for (int j = 0; j < KW; ++j) {
            v2f ab; ab.x = 0.f; ab.y = 0.f;
            float qq = 0.f, pp = 0.f;
            #pragma unroll
            for (int k = 0; k < KW; ++k) {
                float w = wl[k];
                v2f v = base[j * SROW + k];        // ds_read_b64
                ab += w * v;                       // v_pk_fma_f32
                float xy = v.x * v.y;
                float ss = fmaf(v.y, v.y, v.x * v.x);
                pp = fmaf(w, xy, pp);
                qq = fmaf(w, ss, qq);
            }
            rAB[j] = ab;
            v2f qp; qp.x = qq; qp.y = pp;
            rQP[j] = qp;

            const int i = ch * KW + j;             // local h index (uniform)
            if (i >= 10 && i < OUT_R + 10) {       // output row = band*32 + i - 10
                v2f mAB; mAB.x = 0.f; mAB.y = 0.f;
                v2f mQP; mQP.x = 0.f; mQP.y = 0.f;
                #pragma unroll
                for (int m = 0; m < KW; ++m) {     // ring slot for h-row (o-5+m)
                    const int sidx = (j + 1 + m) % KW;  // static per (j,m)
                    float w = wl[m];
                    mAB += w * rAB[sidx];          // v_pk_fma_f32
                    mQP += w * rQP[sidx];
                }
                float mu1 = mAB.x, mu2 = mAB.y, sq = mQP.x, sp = mQP.y;
                float mu1sq = mu1 * mu1, mu2sq = mu2 * mu2, mu12 = mu1 * mu2;
                float musum = mu1sq + mu2sq;
                float num = (2.f * mu12 + C1) * (2.f * (sp - mu12) + C2);
                float den = (musum + C1) * ((sq - musum) + C2);
                acc += num * __builtin_amdgcn_rcpf(den);
            }
        }

        if (ch + 1 < NCHUNK) store_chunk((ch + 1) & 1, ch + 1);
        __syncthreads();
    }

    // --- block reduction + fused global reduce (atomic) ---
    #pragma unroll
    for (int off = 32; off > 0; off >>= 1)
        acc += __shfl_down(acc, off, 64);
    int wave = t >> 6;
    if ((t & 63) == 0) red[wave] = acc;
    __syncthreads();
    if (t == 0) {
        float partial = red[0] + red[1] + red[2] + red[3];
        float v = partial * scale;                 // scale = -1/count
        if (band == 0 && plane == 0) v += 1.0f;    // out = 1 - sum/count
        atomicAdd(out, v);
    }
}

extern "C" void kernel_launch(void* const* d_in, const int* in_sizes, int n_in,
                              void* d_out, int out_size, void* d_ws, size_t ws_size,
                              hipStream_t stream) {
    const float* img1   = (const float*)d_in[0];
    const float* img2   = (const float*)d_in[1];
    const float* window = (const float*)d_in[2];
    float* out = (float*)d_out;

    const int planes = 16 * 9;            // 144
    const int bands = Hd / OUT_R;         // 8

    hipMemsetAsync(out, 0, sizeof(float), stream);

    const float scale = -(float)(1.0 / ((double)planes * Hd * Wd));
    dim3 grid(bands, planes);
    ssim_band_kernel<<<grid, BLOCK, 0, stream>>>(img1, img2, window, out, scale);
}

// Round 6
// 131.627 us; speedup vs baseline: 1.1033x; 1.0478x over previous
//
#include <hip/hip_runtime.h>
#include <math.h>

#define Wd 256
#define Hd 256
#define KW 11
#define OUT_R 32              // output rows per block (band)
#define NROWS 44              // 4 chunks x 11 streamed rows (42 needed)
#define BLOCK 256

typedef float v2f __attribute__((ext_vector_type(2)));

__device__ __forceinline__ float rfl(float v) {
    return __int_as_float(__builtin_amdgcn_readfirstlane(__float_as_int(v)));
}

// Vertical-first SSIM: thread = one column of one (n,c) plane band.
// Raw rows stream from global (coalesced b32, no input LDS). The vertical
// 11-tap conv runs in a 4-channel register ring (slot = j, static, via 11-row
// chunk unroll). Vertical results (A,B | Q=x^2+y^2, P=xy convolved) go to a
// tiny double-buffered LDS row buffer, split into even/odd column arrays so
// the horizontal pass (t<128, 2 adjacent output cols/thread) reads 12
// lane-contiguous ds_read_b128 (conflict-free). Zero conv padding: invalid
// rows simply contribute zero ring slots; column halos zeroed once.
__global__ __launch_bounds__(BLOCK, 4) void ssim_stream_kernel(
    const float* __restrict__ img1, const float* __restrict__ img2,
    const float* __restrict__ window, float* __restrict__ out, float scale)
{
    // rbE[buf][e+2] holds col 2e  (e=-2..130 -> idx 0..132)
    // rbO[buf][o+3] holds col 2o+1 (o=-3..129 -> idx 0..132)
    __shared__ __align__(16) float4 rbE[2][136];
    __shared__ __align__(16) float4 rbO[2][136];   // 2*2*136*16 = 8.7 KB
    __shared__ float red[BLOCK / 64];

    const float C1 = 1e-4f, C2 = 9e-4f;
    const int t = threadIdx.x;
    const int band = blockIdx.x;     // 0..7
    const int plane = blockIdx.y;    // 0..143
    const float* __restrict__ p1 = img1 + (size_t)plane * (Hd * Wd);
    const float* __restrict__ p2 = img2 + (size_t)plane * (Hd * Wd);

    // Separable 1D weights (win2d = a outer a, sum a = 1); pin to SGPRs.
    float wl[KW];
    {
        float c = sqrtf(window[5 * KW + 5]);
        #pragma unroll
        for (int k = 0; k < KW; ++k)
            wl[k] = rfl(window[k * KW + 5] / c);
    }

    // Zero the 20 column-halo cells once (never written by the row pass).
    if (t < 40) {
        int b = t / 20, k = t % 20;
        float4 z = make_float4(0.f, 0.f, 0.f, 0.f);
        if (k < 5)      rbE[b][(k < 2) ? k : (128 + k)] = z;   // 0,1,130,131,132
        else { int q = k - 5; rbO[b][(q < 3) ? q : (128 + q)] = z; } // 0,1,2,131,132
    }

    const int ghbase = band * OUT_R - 5;   // global row of stream index 0

    v2f rXY[KW], rQP[KW];
    float acc = 0.f;

    // prefetch row 0
    float xc = 0.f, yc = 0.f;
    {
        int g = ghbase;
        if ((unsigned)g < (unsigned)Hd) {
            xc = p1[(g << 8) + t];
            yc = p2[(g << 8) + t];
        }
    }

    #pragma unroll 1
    for (int ch = 0; ch < 4; ++ch) {
        #pragma unroll
        for (int j = 0; j < KW; ++j) {
            const int i = ch * KW + j;       // stream index (ch runtime, j static)

            // ring insert row i (invalid rows carry zeros -> zero padding)
            {
                float xy = xc * yc;
                float ss = fmaf(xc, xc, yc * yc);
                v2f t1; t1.x = xc; t1.y = yc; rXY[j] = t1;
                v2f t2; t2.x = ss; t2.y = xy; rQP[j] = t2;
            }

            const bool emit = (i >= 10) && (i < OUT_R + 10);   // block-uniform
            const int buf = i & 1;

            if (emit) {
                // vertical 11-tap conv (rows i-10..i = slots (j+1+m)%11)
                v2f vAB; vAB.x = 0.f; vAB.y = 0.f;
                v2f vQP; vQP.x = 0.f; vQP.y = 0.f;
                #pragma unroll
                for (int m = 0; m < KW; ++m) {
                    const int s = (j + 1 + m) % KW;   // static per (j,m)
                    float w = wl[m];
                    vAB += w * rXY[s];                // v_pk_fma_f32
                    vQP += w * rQP[s];
                }
                float4* dst = (t & 1) ? &rbO[buf][(t >> 1) + 3]
                                      : &rbE[buf][(t >> 1) + 2];
                *dst = make_float4(vAB.x, vAB.y, vQP.x, vQP.y);
                __syncthreads();   // writes visible; prev horizontal done
            }

            // prefetch next row (issued after barrier, consumed next iter
            // BEFORE the next barrier -> no vmcnt drain at barriers)
            {
                int g = ghbase + i + 1;
                if ((unsigned)g < (unsigned)Hd) {
                    xc = p1[(g << 8) + t];
                    yc = p2[(g << 8) + t];
                } else { xc = 0.f; yc = 0.f; }
            }

            if (emit && t < 128) {
                // horizontal 11-tap for output cols 2t, 2t+1
                const float4* bE = &rbE[buf][t];
                const float4* bO = &rbO[buf][t];
                v2f a0, q0, a1, q1;
                a0.x = a0.y = q0.x = q0.y = 0.f;
                a1.x = a1.y = q1.x = q1.y = 0.f;
                #pragma unroll
                for (int k = 0; k < 6; ++k) {
                    float4 vO = bO[k];                    // ds_read_b128
                    v2f oab; oab.x = vO.x; oab.y = vO.y;
                    v2f oqp; oqp.x = vO.z; oqp.y = vO.w;
                    a0 += wl[2 * k] * oab;  q0 += wl[2 * k] * oqp;
                    if (k >= 1) { a1 += wl[2 * k - 1] * oab;  q1 += wl[2 * k - 1] * oqp; }
                    float4 vE = bE[k];                    // ds_read_b128
                    v2f eab; eab.x = vE.x; eab.y = vE.y;
                    v2f eqp; eqp.x = vE.z; eqp.y = vE.w;
                    a1 += wl[2 * k] * eab;  q1 += wl[2 * k] * eqp;
                    if (k <= 4) { a0 += wl[2 * k + 1] * eab;  q0 += wl[2 * k + 1] * eqp; }
                }
                // SSIM epilogue for both outputs
                {
                    float mu1 = a0.x, mu2 = a0.y, sq = q0.x, sp = q0.y;
                    float mu1sq = mu1 * mu1, mu2sq = mu2 * mu2, mu12 = mu1 * mu2;
                    float musum = mu1sq + mu2sq;
                    float num = (2.f * mu12 + C1) * (2.f * (sp - mu12) + C2);
                    float den = (musum + C1) * ((sq - musum) + C2);
                    acc += num * __builtin_amdgcn_rcpf(den);
                }
                {
                    float mu1 = a1.x, mu2 = a1.y, sq = q1.x, sp = q1.y;
                    float mu1sq = mu1 * mu1, mu2sq = mu2 * mu2, mu12 = mu1 * mu2;
                    float musum = mu1sq + mu2sq;
                    float num = (2.f * mu12 + C1) * (2.f * (sp - mu12) + C2);
                    float den = (musum + C1) * ((sq - musum) + C2);
                    acc += num * __builtin_amdgcn_rcpf(den);
                }
            }
        }
    }

    // --- block reduction + fused global reduce (atomic) ---
    #pragma unroll
    for (int off = 32; off > 0; off >>= 1)
        acc += __shfl_down(acc, off, 64);
    int wave = t >> 6;
    if ((t & 63) == 0) red[wave] = acc;
    __syncthreads();
    if (t == 0) {
        float partial = red[0] + red[1] + red[2] + red[3];
        float v = partial * scale;                 // scale = -1/count
        if (band == 0 && plane == 0) v += 1.0f;    // out = 1 - sum/count
        atomicAdd(out, v);
    }
}

extern "C" void kernel_launch(void* const* d_in, const int* in_sizes, int n_in,
                              void* d_out, int out_size, void* d_ws, size_t ws_size,
                              hipStream_t stream) {
    const float* img1   = (const float*)d_in[0];
    const float* img2   = (const float*)d_in[1];
    const float* window = (const float*)d_in[2];
    float* out = (float*)d_out;

    const int planes = 16 * 9;            // 144
    const int bands = Hd / OUT_R;         // 8

    hipMemsetAsync(out, 0, sizeof(float), stream);

    const float scale = -(float)(1.0 / ((double)planes * Hd * Wd));
    dim3 grid(bands, planes);
    ssim_stream_kernel<<<grid, BLOCK, 0, stream>>>(img1, img2, window, out, scale);
}